// Round 1
// baseline (761.937 us; speedup 1.0000x reference)
//
#include <hip/hip_runtime.h>
#include <hip/hip_bf16.h>
#include <math.h>

#define B_ 8
#define NQ_ 1024
#define NK_ 1024
#define DM_ 512
#define H_ 8
#define DK_ 64
#define HDK_ 512
#define LOG2E 1.4426950408889634f

typedef _Float16 half8 __attribute__((ext_vector_type(8)));
typedef _Float16 half4 __attribute__((ext_vector_type(4)));
typedef float f32x4 __attribute__((ext_vector_type(4)));

// ---------------------------------------------------------------------------
// Detect whether attention_mask is stored as 1-byte or 4-byte elements.
// 4-byte elements are words in {0,1} (int) or {0, 0x3F800000} (float 0/1).
// Packed bytes produce words outside that set with probability ~1.
__global__ void detect_mask_kernel(const unsigned int* __restrict__ w, int nwords,
                                   int* __restrict__ flag) {
  __shared__ int s;
  if (threadIdx.x == 0) s = 0;
  __syncthreads();
  int bad = 0;
  for (int i = threadIdx.x; i < nwords; i += blockDim.x) {
    unsigned int v = w[i];
    if (v > 1u && v != 0x3F800000u) bad = 1;
  }
  if (bad) atomicOr(&s, 1);
  __syncthreads();
  if (threadIdx.x == 0) *flag = s;  // 1 => bytes, 0 => 4-byte words
}

// ---------------------------------------------------------------------------
__global__ void cast_f32_f16(const float* __restrict__ src, _Float16* __restrict__ dst,
                             int n4) {
  int i = blockIdx.x * 256 + threadIdx.x;
  if (i < n4) {
    float4 v = ((const float4*)src)[i];
    half4 h;
    h[0] = (_Float16)v.x; h[1] = (_Float16)v.y;
    h[2] = (_Float16)v.z; h[3] = (_Float16)v.w;
    ((half4*)dst)[i] = h;
  }
}

// Transpose+cast the four 512x512 weight matrices: Wt[n][k] = W[k][n]
__global__ void wtrans_kernel(const float* __restrict__ w0, const float* __restrict__ w1,
                              const float* __restrict__ w2, const float* __restrict__ w3,
                              _Float16* __restrict__ t0, _Float16* __restrict__ t1,
                              _Float16* __restrict__ t2, _Float16* __restrict__ t3) {
  const float* W;
  _Float16* T;
  switch (blockIdx.y) {
    case 0: W = w0; T = t0; break;
    case 1: W = w1; T = t1; break;
    case 2: W = w2; T = t2; break;
    default: W = w3; T = t3; break;
  }
  int t = blockIdx.x * 256 + threadIdx.x;  // 262144 total
  int n = t & 511, k = t >> 9;
  T[(size_t)n * 512 + k] = (_Float16)W[(size_t)k * 512 + n];
}

// ---------------------------------------------------------------------------
// Generic 8192x512x512 fp16 MFMA GEMM, Bt is B^T (N x K row-major).
// mode 0: Q epilogue  -> Qp   (B,H,NQ,DK) f16, scaled by log2e/8
// mode 1: K epilogue  -> Kg   (B,H,NK,DK) f16, gated by mm
// mode 2: V epilogue  -> Vgt  (B,H,DK,NK) f16, gated by mm (transposed store)
// mode 3: O epilogue  -> out  (8192x512)  f32, + bias
__global__ __launch_bounds__(256)
void gemm_kernel(const _Float16* __restrict__ A, const _Float16* __restrict__ Bt,
                 const float* __restrict__ bias, const float* __restrict__ mem,
                 const float* __restrict__ Wmm, const float* __restrict__ bmm,
                 void* __restrict__ outp, const int mode) {
  __shared__ _Float16 As[128 * 32];
  __shared__ _Float16 Bs[128 * 32];
  const int tid = threadIdx.x;
  const int lane = tid & 63, wave = tid >> 6;
  const int wr = wave >> 1, wc = wave & 1;
  const int l15 = lane & 15, l4 = lane >> 4;
  const int row0 = blockIdx.x * 128, col0 = blockIdx.y * 128;
  const int srow = tid >> 1;         // 0..127
  const int sc0 = (tid & 1) * 2;     // chunk base (16B chunks, 4/row)

  f32x4 acc[4][4] = {};

  for (int k0 = 0; k0 < 512; k0 += 32) {
    __syncthreads();
    const _Float16* sa = A + (size_t)(row0 + srow) * 512 + k0;
    const _Float16* sb = Bt + (size_t)(col0 + srow) * 512 + k0;
#pragma unroll
    for (int c = 0; c < 2; ++c) {
      int ci = sc0 + c;
      float4 va = *(const float4*)(sa + ci * 8);
      float4 vb = *(const float4*)(sb + ci * 8);
      int cd = ci ^ (srow & 3);  // bank-conflict XOR swizzle
      *(float4*)((char*)As + srow * 64 + (cd << 4)) = va;
      *(float4*)((char*)Bs + srow * 64 + (cd << 4)) = vb;
    }
    __syncthreads();
    half8 af[4], bf[4];
#pragma unroll
    for (int mi = 0; mi < 4; ++mi) {
      int r = wr * 64 + mi * 16 + l15;
      af[mi] = *(half8*)((char*)As + r * 64 + ((l4 ^ (r & 3)) << 4));
    }
#pragma unroll
    for (int ni = 0; ni < 4; ++ni) {
      int r = wc * 64 + ni * 16 + l15;
      bf[ni] = *(half8*)((char*)Bs + r * 64 + ((l4 ^ (r & 3)) << 4));
    }
#pragma unroll
    for (int mi = 0; mi < 4; ++mi)
#pragma unroll
      for (int ni = 0; ni < 4; ++ni)
        acc[mi][ni] =
            __builtin_amdgcn_mfma_f32_16x16x32_f16(af[mi], bf[ni], acc[mi][ni], 0, 0, 0);
  }

  // Epilogue. C/D frag: col = lane&15, row = (lane>>4)*4 + reg.
#pragma unroll
  for (int mi = 0; mi < 4; ++mi) {
#pragma unroll
    for (int ni = 0; ni < 4; ++ni) {
      const int gc = col0 + wc * 64 + ni * 16 + l15;
      const float bi = bias[gc];
      const int h = gc >> 6, d = gc & 63;
#pragma unroll
      for (int reg = 0; reg < 4; ++reg) {
        const int gr = row0 + wr * 64 + mi * 16 + l4 * 4 + reg;
        float val = acc[mi][ni][reg] + bi;
        if (mode == 3) {
          ((float*)outp)[(size_t)gr * 512 + gc] = val;
        } else if (mode == 0) {
          const int b = gr >> 10, n = gr & 1023;
          ((_Float16*)outp)[((size_t)(b * 8 + h) * 1024 + n) * 64 + d] =
              (_Float16)(val * (LOG2E / 8.0f));
        } else {
          const int b = gr >> 10, n = gr & 1023;
          float mmv = fmaf(mem[gr], Wmm[gc], bmm[gc]);
          float g = val * mmv;
          if (mode == 1)
            ((_Float16*)outp)[((size_t)(b * 8 + h) * 1024 + n) * 64 + d] = (_Float16)g;
          else
            ((_Float16*)outp)[((size_t)(b * 8 + h) * 64 + d) * 1024 + n] = (_Float16)g;
        }
      }
    }
  }
}

// ---------------------------------------------------------------------------
// Flash attention with gated K/V, per-element weight * score, log2(geometry)
// bias, boolean exclusion mask. Base-2 online softmax (log2e/8 pre-folded
// into Q). Block = 4 waves, 64 q rows (16/wave); k-tiles of 128.
__global__ __launch_bounds__(256)
void attn_kernel(const _Float16* __restrict__ Qp, const _Float16* __restrict__ Kg,
                 const _Float16* __restrict__ Vgt, const float* __restrict__ attw,
                 const float* __restrict__ geom, const void* __restrict__ maskp,
                 const int* __restrict__ flagp, _Float16* __restrict__ Ocat) {
  __shared__ _Float16 Ks[128 * 64];       // [key][d], 128B rows, XOR swizzled
  __shared__ _Float16 Vs[64 * 128];       // [d][key], 256B rows, XOR swizzled
  __shared__ _Float16 Ps[4][16 * 128];    // per-wave P tile, 256B rows, swizzled

  const int tid = threadIdx.x;
  const int lane = tid & 63, wave = tid >> 6;
  const int l15 = lane & 15, l4 = lane >> 4;
  const int h = blockIdx.y, b = blockIdx.z;
  const int bh = b * H_ + h;
  const int qb = blockIdx.x * 64 + wave * 16;
  const int maskBytes = *flagp;
  const unsigned char* m8 = (const unsigned char*)maskp;
  const int* m32 = (const int*)maskp;

  // Q A-frags (A[row=l&15][kk=(l>>4)*8+j]), DK=64 -> 2 kk-steps of 32
  half8 aq[2];
  {
    const _Float16* qsrc = Qp + ((size_t)bh * NQ_ + (qb + l15)) * DK_;
#pragma unroll
    for (int s = 0; s < 2; ++s) aq[s] = *(const half8*)(qsrc + s * 32 + l4 * 8);
  }

  f32x4 fo[4] = {};
  float mrun[4], lrun[4];
#pragma unroll
  for (int r = 0; r < 4; ++r) { mrun[r] = -INFINITY; lrun[r] = 0.f; }

  const int krow = tid >> 1;          // 0..127 (key rows, 8 chunks of 16B)
  const int kc0 = (tid & 1) * 4;
  const int vrow = tid >> 2;          // 0..63  (d rows, 16 chunks of 16B)
  const int vc0 = (tid & 3) * 4;

  for (int kt = 0; kt < NK_ / 128; ++kt) {
    __syncthreads();
    {
      const _Float16* ks = Kg + ((size_t)bh * NK_ + kt * 128 + krow) * DK_;
#pragma unroll
      for (int c = 0; c < 4; ++c) {
        int ci = kc0 + c;
        float4 v = *(const float4*)(ks + ci * 8);
        *(float4*)((char*)Ks + krow * 128 + (((ci ^ (krow & 7))) << 4)) = v;
      }
      const _Float16* vsp = Vgt + ((size_t)bh * DK_ + vrow) * NK_ + kt * 128;
#pragma unroll
      for (int c = 0; c < 4; ++c) {
        int ci = vc0 + c;
        float4 v = *(const float4*)(vsp + ci * 8);
        *(float4*)((char*)Vs + vrow * 256 + (((ci ^ (vrow & 7))) << 4)) = v;
      }
    }
    __syncthreads();

    // ---- QK^T: 8 col-frags x 2 kk-steps
    f32x4 sf[8];
#pragma unroll
    for (int c = 0; c < 8; ++c) {
      sf[c] = (f32x4){0.f, 0.f, 0.f, 0.f};
#pragma unroll
      for (int s = 0; s < 2; ++s) {
        int r = c * 16 + l15;
        half8 bk = *(half8*)((char*)Ks + r * 128 + (((s * 4 + l4) ^ (r & 7)) << 4));
        sf[c] = __builtin_amdgcn_mfma_f32_16x16x32_f16(aq[s], bk, sf[c], 0, 0, 0);
      }
    }

    // ---- per-element: t = log2(max(g,1e-6)) + s*w  (masked -> -inf)
    const int kbase = kt * 128;
#pragma unroll
    for (int c = 0; c < 8; ++c) {
      const int kg = kbase + c * 16 + l15;
#pragma unroll
      for (int reg = 0; reg < 4; ++reg) {
        const int qg = qb + l4 * 4 + reg;
        const size_t idx = ((size_t)bh << 20) + (size_t)qg * NK_ + kg;
        bool msk;
        if (maskBytes) msk = (m8[idx] != 0);
        else           msk = (m32[idx] != 0);
        float t;
        if (msk) {
          t = -INFINITY;
        } else {
          float wv = attw[idx];
          float gv = geom[idx];
          t = __log2f(fmaxf(gv, 1e-6f)) + sf[c][reg] * wv;
        }
        sf[c][reg] = t;
      }
    }

    // ---- online softmax (rows live in 16-lane groups; reg indexes row%4)
    float scl[4];
#pragma unroll
    for (int reg = 0; reg < 4; ++reg) {
      float mx = sf[0][reg];
#pragma unroll
      for (int c = 1; c < 8; ++c) mx = fmaxf(mx, sf[c][reg]);
      mx = fmaxf(mx, __shfl_xor(mx, 1));
      mx = fmaxf(mx, __shfl_xor(mx, 2));
      mx = fmaxf(mx, __shfl_xor(mx, 4));
      mx = fmaxf(mx, __shfl_xor(mx, 8));
      float mn = fmaxf(mrun[reg], mx);
      float sc = (mrun[reg] == -INFINITY) ? 0.f : exp2f(mrun[reg] - mn);
      mrun[reg] = mn;
      lrun[reg] *= sc;
      scl[reg] = sc;
    }
#pragma unroll
    for (int c = 0; c < 4; ++c)
#pragma unroll
      for (int reg = 0; reg < 4; ++reg) fo[c][reg] *= scl[reg];

    float rs[4] = {0.f, 0.f, 0.f, 0.f};
#pragma unroll
    for (int c = 0; c < 8; ++c)
#pragma unroll
      for (int reg = 0; reg < 4; ++reg) {
        float t = sf[c][reg];
        float p = (t == -INFINITY) ? 0.f : exp2f(t - mrun[reg]);
        sf[c][reg] = p;
        rs[reg] += p;
      }
#pragma unroll
    for (int reg = 0; reg < 4; ++reg) {
      float s = rs[reg];
      s += __shfl_xor(s, 1);
      s += __shfl_xor(s, 2);
      s += __shfl_xor(s, 4);
      s += __shfl_xor(s, 8);
      lrun[reg] += s;
    }

    // ---- write P (f16) to this wave's LDS region (no barrier needed)
    _Float16* pw = &Ps[wave][0];
#pragma unroll
    for (int c = 0; c < 8; ++c) {
      const int k = c * 16 + l15;
#pragma unroll
      for (int reg = 0; reg < 4; ++reg) {
        const int rq = l4 * 4 + reg;
        int byte = rq * 256 + (((k >> 3) ^ (rq & 7)) << 4) + (k & 7) * 2;
        *(_Float16*)((char*)pw + byte) = (_Float16)sf[c][reg];
      }
    }

    // ---- PV: A = P (row=q, kk=key), B = Vs (kk=key, col=d)
#pragma unroll
    for (int s4 = 0; s4 < 4; ++s4) {
      half8 pa = *(half8*)((char*)pw + l15 * 256 + (((s4 * 4 + l4) ^ (l15 & 7)) << 4));
#pragma unroll
      for (int c = 0; c < 4; ++c) {
        int rd = c * 16 + l15;
        half8 bv = *(half8*)((char*)Vs + rd * 256 + (((s4 * 4 + l4) ^ (rd & 7)) << 4));
        fo[c] = __builtin_amdgcn_mfma_f32_16x16x32_f16(pa, bv, fo[c], 0, 0, 0);
      }
    }
  }

  // ---- normalize + store Ocat (b, q, h*64+d) f16
#pragma unroll
  for (int reg = 0; reg < 4; ++reg) {
    const int qg = qb + l4 * 4 + reg;
    const float rinv = 1.0f / lrun[reg];
#pragma unroll
    for (int c = 0; c < 4; ++c) {
      const int d = c * 16 + l15;
      Ocat[((size_t)b * NQ_ + qg) * HDK_ + h * DK_ + d] = (_Float16)(fo[c][reg] * rinv);
    }
  }
}

// ---------------------------------------------------------------------------
extern "C" void kernel_launch(void* const* d_in, const int* in_sizes, int n_in,
                              void* d_out, int out_size, void* d_ws, size_t ws_size,
                              hipStream_t stream) {
  (void)in_sizes; (void)n_in; (void)out_size; (void)ws_size;
  const float* queries = (const float*)d_in[0];
  const float* keys    = (const float*)d_in[1];
  const float* values  = (const float*)d_in[2];
  const void*  maskp   = d_in[3];
  const float* attw    = (const float*)d_in[4];
  const float* memo    = (const float*)d_in[5];
  const float* geom    = (const float*)d_in[6];
  const float* Wq = (const float*)d_in[7];
  const float* bq = (const float*)d_in[8];
  const float* Wk = (const float*)d_in[9];
  const float* bk = (const float*)d_in[10];
  const float* Wv = (const float*)d_in[11];
  const float* bv = (const float*)d_in[12];
  const float* Wmm = (const float*)d_in[13];
  const float* bmm = (const float*)d_in[14];
  const float* Wo = (const float*)d_in[15];
  const float* bo = (const float*)d_in[16];

  char* ws = (char*)d_ws;
  size_t off = 0;
  auto alloc = [&](size_t bytes) {
    char* p = ws + off;
    off += (bytes + 255) & ~(size_t)255;
    return p;
  };
  const size_t MAT = (size_t)8192 * 512 * 2;  // 8 MiB fp16
  int* flag = (int*)alloc(256);
  _Float16* qh  = (_Float16*)alloc(MAT);
  _Float16* kh  = (_Float16*)alloc(MAT);
  _Float16* vh  = (_Float16*)alloc(MAT);
  _Float16* Wtq = (_Float16*)alloc((size_t)512 * 512 * 2);
  _Float16* Wtk = (_Float16*)alloc((size_t)512 * 512 * 2);
  _Float16* Wtv = (_Float16*)alloc((size_t)512 * 512 * 2);
  _Float16* Wto = (_Float16*)alloc((size_t)512 * 512 * 2);
  _Float16* Qp   = (_Float16*)alloc(MAT);
  _Float16* Kgp  = (_Float16*)alloc(MAT);
  _Float16* Vgtp = (_Float16*)alloc(MAT);
  _Float16* Ocat = (_Float16*)alloc(MAT);

  detect_mask_kernel<<<1, 256, 0, stream>>>((const unsigned int*)maskp, 65536, flag);

  const int n4 = 8192 * 512 / 4;
  cast_f32_f16<<<n4 / 256, 256, 0, stream>>>(queries, qh, n4);
  cast_f32_f16<<<n4 / 256, 256, 0, stream>>>(keys, kh, n4);
  cast_f32_f16<<<n4 / 256, 256, 0, stream>>>(values, vh, n4);
  wtrans_kernel<<<dim3(1024, 4), 256, 0, stream>>>(Wq, Wk, Wv, Wo, Wtq, Wtk, Wtv, Wto);

  dim3 ggrid(64, 4);
  gemm_kernel<<<ggrid, 256, 0, stream>>>(qh, Wtq, bq, nullptr, nullptr, nullptr, Qp, 0);
  gemm_kernel<<<ggrid, 256, 0, stream>>>(kh, Wtk, bk, memo, Wmm, bmm, Kgp, 1);
  gemm_kernel<<<ggrid, 256, 0, stream>>>(vh, Wtv, bv, memo, Wmm, bmm, Vgtp, 2);

  attn_kernel<<<dim3(16, 8, 8), 256, 0, stream>>>(Qp, Kgp, Vgtp, attw, geom, maskp,
                                                  flag, Ocat);

  gemm_kernel<<<ggrid, 256, 0, stream>>>(Ocat, Wto, bo, nullptr, nullptr, nullptr,
                                         d_out, 3);
}

// Round 3
// 409.710 us; speedup vs baseline: 1.8597x; 1.8597x over previous
//
#include <hip/hip_runtime.h>
#include <hip/hip_bf16.h>
#include <math.h>

#define B_ 8
#define NQ_ 1024
#define NK_ 1024
#define H_ 8
#define DK_ 64
#define HDK_ 512
#define LOG2E 1.4426950408889634f

typedef _Float16 half8 __attribute__((ext_vector_type(8)));
typedef _Float16 half4 __attribute__((ext_vector_type(4)));
typedef float f32x4 __attribute__((ext_vector_type(4)));

// ---------------------------------------------------------------------------
// Detect whether attention_mask is stored as 1-byte or 4-byte elements.
__global__ void detect_mask_kernel(const unsigned int* __restrict__ w, int nwords,
                                   int* __restrict__ flag) {
  __shared__ int s;
  if (threadIdx.x == 0) s = 0;
  __syncthreads();
  int bad = 0;
  for (int i = threadIdx.x; i < nwords; i += blockDim.x) {
    unsigned int v = w[i];
    if (v > 1u && v != 0x3F800000u) bad = 1;
  }
  if (bad) atomicOr(&s, 1);
  __syncthreads();
  if (threadIdx.x == 0) *flag = s;  // 1 => bytes, 0 => 4-byte words
}

// ---------------------------------------------------------------------------
// Transpose+cast 512x512 weight matrices via LDS tiles: Wt[n][k] = W[k][n]
__global__ __launch_bounds__(256)
void wtrans_kernel(const float* __restrict__ w0, const float* __restrict__ w1,
                   const float* __restrict__ w2, const float* __restrict__ w3,
                   _Float16* __restrict__ t0, _Float16* __restrict__ t1,
                   _Float16* __restrict__ t2, _Float16* __restrict__ t3) {
  __shared__ float tile[64][65];
  const float* W;
  _Float16* T;
  switch (blockIdx.y) {
    case 0: W = w0; T = t0; break;
    case 1: W = w1; T = t1; break;
    case 2: W = w2; T = t2; break;
    default: W = w3; T = t3; break;
  }
  const int t = blockIdx.x;              // 64 tiles
  const int k0 = (t >> 3) * 64, n0 = (t & 7) * 64;
  const int tid = threadIdx.x;
  const int r = tid >> 4, c4 = (tid & 15) * 4;
#pragma unroll
  for (int i = 0; i < 4; ++i) {
    const int kk = r + i * 16;
    float4 v = *(const float4*)(W + (size_t)(k0 + kk) * 512 + n0 + c4);
    tile[kk][c4 + 0] = v.x;
    tile[kk][c4 + 1] = v.y;
    tile[kk][c4 + 2] = v.z;
    tile[kk][c4 + 3] = v.w;
  }
  __syncthreads();
#pragma unroll
  for (int i = 0; i < 4; ++i) {
    const int nn = r + i * 16;
    half4 h;
#pragma unroll
    for (int j = 0; j < 4; ++j) h[j] = (_Float16)tile[c4 + j][nn];
    *(half4*)(T + (size_t)(n0 + nn) * 512 + k0 + c4) = h;
  }
}

// ---------------------------------------------------------------------------
// 8192x512x512 fp16 MFMA GEMM. A is f32 (cast in staging) except mode 3 (f16).
// mode 0: Q epilogue  -> Qp   (B,H,NQ,DK) f16, scaled by log2e/8
// mode 1: K epilogue  -> Kg   (B,H,NK,DK) f16, gated by mm
// mode 2: V epilogue  -> Vgt  (B,H,DK,NK) f16, gated by mm (transposed store)
// mode 3: O epilogue  -> out  (8192x512)  f32, + bias
__global__ __launch_bounds__(256)
void gemm_kernel(const float* __restrict__ A32, const _Float16* __restrict__ A16,
                 const _Float16* __restrict__ Bt, const float* __restrict__ bias,
                 const float* __restrict__ mem, const float* __restrict__ Wmm,
                 const float* __restrict__ bmm, void* __restrict__ outp,
                 const int mode) {
  __shared__ _Float16 As[128 * 32];
  __shared__ _Float16 Bs[128 * 32];
  const int tid = threadIdx.x;
  const int lane = tid & 63, wave = tid >> 6;
  const int wr = wave >> 1, wc = wave & 1;
  const int l15 = lane & 15, l4 = lane >> 4;
  const int row0 = blockIdx.x * 128, col0 = blockIdx.y * 128;
  const int srow = tid >> 1;
  const int sc0 = (tid & 1) * 2;

  f32x4 acc[4][4] = {};

  for (int k0 = 0; k0 < 512; k0 += 32) {
    __syncthreads();
    const _Float16* sb = Bt + (size_t)(col0 + srow) * 512 + k0;
#pragma unroll
    for (int c = 0; c < 2; ++c) {
      int ci = sc0 + c;
      half8 ha;
      if (mode == 3) {
        ha = *(const half8*)(A16 + (size_t)(row0 + srow) * 512 + k0 + ci * 8);
      } else {
        const float* s = A32 + (size_t)(row0 + srow) * 512 + k0 + ci * 8;
        float4 x = *(const float4*)s;
        float4 y = *(const float4*)(s + 4);
        ha[0] = (_Float16)x.x; ha[1] = (_Float16)x.y;
        ha[2] = (_Float16)x.z; ha[3] = (_Float16)x.w;
        ha[4] = (_Float16)y.x; ha[5] = (_Float16)y.y;
        ha[6] = (_Float16)y.z; ha[7] = (_Float16)y.w;
      }
      float4 vb = *(const float4*)(sb + ci * 8);
      int cd = ci ^ (srow & 3);
      *(half8*)((char*)As + srow * 64 + (cd << 4)) = ha;
      *(float4*)((char*)Bs + srow * 64 + (cd << 4)) = vb;
    }
    __syncthreads();
    half8 af[4], bf[4];
#pragma unroll
    for (int mi = 0; mi < 4; ++mi) {
      int r = wr * 64 + mi * 16 + l15;
      af[mi] = *(half8*)((char*)As + r * 64 + ((l4 ^ (r & 3)) << 4));
    }
#pragma unroll
    for (int ni = 0; ni < 4; ++ni) {
      int r = wc * 64 + ni * 16 + l15;
      bf[ni] = *(half8*)((char*)Bs + r * 64 + ((l4 ^ (r & 3)) << 4));
    }
#pragma unroll
    for (int mi = 0; mi < 4; ++mi)
#pragma unroll
      for (int ni = 0; ni < 4; ++ni)
        acc[mi][ni] =
            __builtin_amdgcn_mfma_f32_16x16x32_f16(af[mi], bf[ni], acc[mi][ni], 0, 0, 0);
  }

#pragma unroll
  for (int mi = 0; mi < 4; ++mi) {
#pragma unroll
    for (int ni = 0; ni < 4; ++ni) {
      const int gc = col0 + wc * 64 + ni * 16 + l15;
      const float bi = bias[gc];
      const int h = gc >> 6, d = gc & 63;
#pragma unroll
      for (int reg = 0; reg < 4; ++reg) {
        const int gr = row0 + wr * 64 + mi * 16 + l4 * 4 + reg;
        float val = acc[mi][ni][reg] + bi;
        if (mode == 3) {
          ((float*)outp)[(size_t)gr * 512 + gc] = val;
        } else if (mode == 0) {
          const int b = gr >> 10, n = gr & 1023;
          ((_Float16*)outp)[((size_t)(b * 8 + h) * 1024 + n) * 64 + d] =
              (_Float16)(val * (LOG2E / 8.0f));
        } else {
          const int b = gr >> 10, n = gr & 1023;
          float mmv = fmaf(mem[gr], Wmm[gc], bmm[gc]);
          float g = val * mmv;
          if (mode == 1)
            ((_Float16*)outp)[((size_t)(b * 8 + h) * 1024 + n) * 64 + d] = (_Float16)g;
          else
            ((_Float16*)outp)[((size_t)(b * 8 + h) * 64 + d) * 1024 + n] = (_Float16)g;
        }
      }
    }
  }
}

// ---------------------------------------------------------------------------
// Flash attention, swapped-operand QK^T (rows=k, cols=q) so each lane owns 4
// consecutive k per fragment -> float4 loads of attw/geom/mask. K-tile = 64,
// 4 waves x 16 q rows, LDS 24 KB -> 4 blocks/CU.
__global__ __launch_bounds__(256, 4)
void attn_kernel(const _Float16* __restrict__ Qp, const _Float16* __restrict__ Kg,
                 const _Float16* __restrict__ Vgt, const float* __restrict__ attw,
                 const float* __restrict__ geom, const void* __restrict__ maskp,
                 const int* __restrict__ flagp, _Float16* __restrict__ Ocat) {
  __shared__ _Float16 Ks[64 * 64];     // [k][d], 128B rows, XOR swizzled
  __shared__ _Float16 Vs[64 * 64];     // [d][k], 128B rows, XOR swizzled
  __shared__ _Float16 Ps[4][16 * 64];  // per-wave P, [q][k], swizzled

  const int tid = threadIdx.x;
  const int lane = tid & 63, wave = tid >> 6;
  const int l15 = lane & 15, l4 = lane >> 4;
  const int h = blockIdx.y, b = blockIdx.z;
  const int bh = b * H_ + h;
  const int qb = blockIdx.x * 64 + wave * 16;
  const int kq = qb + l15;  // this lane's q row
  const int maskBytes = *flagp;
  const unsigned char* m8 = (const unsigned char*)maskp;
  const int* m32 = (const int*)maskp;

  // Q as B-operand: B[col=l15=q][kk=d], d = s*32 + l4*8 + j
  half8 aq[2];
  {
    const _Float16* qsrc = Qp + ((size_t)bh * NQ_ + kq) * DK_;
#pragma unroll
    for (int s = 0; s < 2; ++s) aq[s] = *(const half8*)(qsrc + s * 32 + l4 * 8);
  }

  f32x4 fo[4] = {};           // O accum: row=q-local(l4*4+reg), col=d(c*16+l15)
  float mrun = -INFINITY, lrun = 0.f;

  const int srow = tid >> 2;        // 0..63 staging row
  const int sc0 = (tid & 3) * 2;    // 2 x 16B chunks per thread

  const size_t wgBase = ((size_t)bh << 20) + (size_t)kq * NK_ + l4 * 4;

  float4 wv[4], gv[4];
  unsigned mk[4];
  auto loadWG = [&](int kt) {
    const size_t base = wgBase + kt * 64;
#pragma unroll
    for (int c = 0; c < 4; ++c) {
      wv[c] = *(const float4*)(attw + base + c * 16);
      gv[c] = *(const float4*)(geom + base + c * 16);
      if (maskBytes) {
        unsigned v = *(const unsigned*)(m8 + base + c * 16);
        mk[c] = ((v & 0xffu) ? 1u : 0u) | ((v & 0xff00u) ? 2u : 0u) |
                ((v & 0xff0000u) ? 4u : 0u) | ((v & 0xff000000u) ? 8u : 0u);
      } else {
        int4 v = *(const int4*)(m32 + base + c * 16);
        mk[c] = (v.x ? 1u : 0u) | (v.y ? 2u : 0u) | (v.z ? 4u : 0u) | (v.w ? 8u : 0u);
      }
    }
  };

  loadWG(0);

  for (int kt = 0; kt < NK_ / 64; ++kt) {
    __syncthreads();
    {
      const _Float16* ks = Kg + ((size_t)bh * NK_ + kt * 64 + srow) * DK_ + sc0 * 8;
      const _Float16* vs = Vgt + ((size_t)bh * DK_ + srow) * NK_ + kt * 64 + sc0 * 8;
#pragma unroll
      for (int c = 0; c < 2; ++c) {
        int ci = sc0 + c;
        float4 kv = *(const float4*)(ks + c * 8);
        float4 vv = *(const float4*)(vs + c * 8);
        *(float4*)((char*)Ks + srow * 128 + ((ci ^ (srow & 7)) << 4)) = kv;
        *(float4*)((char*)Vs + srow * 128 + ((ci ^ (srow & 7)) << 4)) = vv;
      }
    }
    __syncthreads();

    // QK^T swapped: A = K rows (k), B = Q cols (q).
    f32x4 sf[4];
#pragma unroll
    for (int c = 0; c < 4; ++c) {
      sf[c] = (f32x4){0.f, 0.f, 0.f, 0.f};
#pragma unroll
      for (int s = 0; s < 2; ++s) {
        int r = c * 16 + l15;
        half8 ak = *(half8*)((char*)Ks + r * 128 + (((s * 4 + l4) ^ (r & 7)) << 4));
        sf[c] = __builtin_amdgcn_mfma_f32_16x16x32_f16(ak, aq[s], sf[c], 0, 0, 0);
      }
    }

    // scores: lane holds q=kq, k = kt*64 + c*16 + l4*4 + reg
#pragma unroll
    for (int c = 0; c < 4; ++c) {
#pragma unroll
      for (int reg = 0; reg < 4; ++reg) {
        float t;
        if ((mk[c] >> reg) & 1u)
          t = -INFINITY;
        else
          t = fmaf(sf[c][reg], wv[c][reg], __log2f(fmaxf(gv[c][reg], 1e-6f)));
        sf[c][reg] = t;
      }
    }

    if (kt + 1 < NK_ / 64) loadWG(kt + 1);  // prefetch next tile's streams

    // online softmax; row q lives in lanes {l15, l15+16, l15+32, l15+48}
    float mx = -INFINITY;
#pragma unroll
    for (int c = 0; c < 4; ++c)
#pragma unroll
      for (int reg = 0; reg < 4; ++reg) mx = fmaxf(mx, sf[c][reg]);
    mx = fmaxf(mx, __shfl_xor(mx, 16));
    mx = fmaxf(mx, __shfl_xor(mx, 32));
    float mn = fmaxf(mrun, mx);
    float sc = (mrun == -INFINITY) ? 0.f : exp2f(mrun - mn);
    mrun = mn;
    lrun *= sc;

    float scq[4];
#pragma unroll
    for (int reg = 0; reg < 4; ++reg) scq[reg] = __shfl(sc, l4 * 4 + reg);
#pragma unroll
    for (int c = 0; c < 4; ++c)
#pragma unroll
      for (int reg = 0; reg < 4; ++reg) fo[c][reg] *= scq[reg];

    float rs = 0.f;
#pragma unroll
    for (int c = 0; c < 4; ++c)
#pragma unroll
      for (int reg = 0; reg < 4; ++reg) {
        float t = sf[c][reg];
        float p = (t == -INFINITY) ? 0.f : exp2f(t - mrun);
        sf[c][reg] = p;
        rs += p;
      }
    rs += __shfl_xor(rs, 16);
    rs += __shfl_xor(rs, 32);
    lrun += rs;

    // P -> LDS [q=l15][k = c*16 + l4*4 + reg], swizzled 16B chunks
    char* pw = (char*)&Ps[wave][0];
#pragma unroll
    for (int c = 0; c < 4; ++c) {
      half4 hp;
#pragma unroll
      for (int reg = 0; reg < 4; ++reg) hp[reg] = (_Float16)sf[c][reg];
      int ci = c * 2 + (l4 >> 1);
      *(half4*)(pw + l15 * 128 + ((ci ^ (l15 & 7)) << 4) + (l4 & 1) * 8) = hp;
    }

    // PV: A = P[q][k], B = Vs[d][k]
#pragma unroll
    for (int s4 = 0; s4 < 2; ++s4) {
      half8 pa = *(half8*)(pw + l15 * 128 + (((s4 * 4 + l4) ^ (l15 & 7)) << 4));
#pragma unroll
      for (int c = 0; c < 4; ++c) {
        int rd = c * 16 + l15;
        half8 bv = *(half8*)((char*)Vs + rd * 128 + (((s4 * 4 + l4) ^ (rd & 7)) << 4));
        fo[c] = __builtin_amdgcn_mfma_f32_16x16x32_f16(pa, bv, fo[c], 0, 0, 0);
      }
    }
  }

  // normalize + store; fo rows are q-local = l4*4+reg -> shuffle lrun
  float rinv[4];
#pragma unroll
  for (int reg = 0; reg < 4; ++reg) rinv[reg] = 1.0f / __shfl(lrun, l4 * 4 + reg);
#pragma unroll
  for (int c = 0; c < 4; ++c) {
    const int d = c * 16 + l15;
#pragma unroll
    for (int reg = 0; reg < 4; ++reg) {
      const int qg = qb + l4 * 4 + reg;
      Ocat[((size_t)b * NQ_ + qg) * HDK_ + h * DK_ + d] = (_Float16)(fo[c][reg] * rinv[reg]);
    }
  }
}

// ---------------------------------------------------------------------------
extern "C" void kernel_launch(void* const* d_in, const int* in_sizes, int n_in,
                              void* d_out, int out_size, void* d_ws, size_t ws_size,
                              hipStream_t stream) {
  (void)in_sizes; (void)n_in; (void)out_size; (void)ws_size;
  const float* queries = (const float*)d_in[0];
  const float* keys    = (const float*)d_in[1];
  const float* values  = (const float*)d_in[2];
  const void*  maskp   = d_in[3];
  const float* attw    = (const float*)d_in[4];
  const float* memo    = (const float*)d_in[5];
  const float* geom    = (const float*)d_in[6];
  const float* Wq = (const float*)d_in[7];
  const float* bq = (const float*)d_in[8];
  const float* Wk = (const float*)d_in[9];
  const float* bk = (const float*)d_in[10];
  const float* Wv = (const float*)d_in[11];
  const float* bv = (const float*)d_in[12];
  const float* Wmm = (const float*)d_in[13];
  const float* bmm = (const float*)d_in[14];
  const float* Wo = (const float*)d_in[15];
  const float* bo = (const float*)d_in[16];

  char* ws = (char*)d_ws;
  size_t off = 0;
  auto alloc = [&](size_t bytes) {
    char* p = ws + off;
    off += (bytes + 255) & ~(size_t)255;
    return p;
  };
  const size_t MAT = (size_t)8192 * 512 * 2;  // 8 MiB fp16
  int* flag = (int*)alloc(256);
  _Float16* Wtq = (_Float16*)alloc((size_t)512 * 512 * 2);
  _Float16* Wtk = (_Float16*)alloc((size_t)512 * 512 * 2);
  _Float16* Wtv = (_Float16*)alloc((size_t)512 * 512 * 2);
  _Float16* Wto = (_Float16*)alloc((size_t)512 * 512 * 2);
  _Float16* Qp   = (_Float16*)alloc(MAT);
  _Float16* Kgp  = (_Float16*)alloc(MAT);
  _Float16* Vgtp = (_Float16*)alloc(MAT);
  _Float16* Ocat = (_Float16*)alloc(MAT);

  detect_mask_kernel<<<1, 256, 0, stream>>>((const unsigned int*)maskp, 4096, flag);
  wtrans_kernel<<<dim3(64, 4), 256, 0, stream>>>(Wq, Wk, Wv, Wo, Wtq, Wtk, Wtv, Wto);

  dim3 ggrid(64, 4);
  gemm_kernel<<<ggrid, 256, 0, stream>>>(queries, nullptr, Wtq, bq, nullptr, nullptr,
                                         nullptr, Qp, 0);
  gemm_kernel<<<ggrid, 256, 0, stream>>>(keys, nullptr, Wtk, bk, memo, Wmm, bmm, Kgp, 1);
  gemm_kernel<<<ggrid, 256, 0, stream>>>(values, nullptr, Wtv, bv, memo, Wmm, bmm,
                                         Vgtp, 2);

  attn_kernel<<<dim3(16, 8, 8), 256, 0, stream>>>(Qp, Kgp, Vgtp, attw, geom, maskp,
                                                  flag, Ocat);

  gemm_kernel<<<ggrid, 256, 0, stream>>>(nullptr, Ocat, Wto, bo, nullptr, nullptr,
                                         nullptr, d_out, 3);
}